// Round 5
// baseline (128.572 us; speedup 1.0000x reference)
//
#include <hip/hip_runtime.h>
#include <math.h>

#define BB 8
#define CC 64
#define HH 32
#define WW 32
#define HW 1024
#define NEGN 256
#define TEMP 2.0f
#define FACTOR 0.8f
#define EPSF 1e-8f
#define PT 4            // p-rows per block
#define NTILE 256       // blocks per sample = HW / PT

// ws layout (floats): accSim[BB*NEGN], accSim0[BB]

__global__ __launch_bounds__(256) void init_acc(float* __restrict__ acc) {
    const int i = blockIdx.x * 256 + threadIdx.x;
    if (i < BB * NEGN + BB) acc[i] = 0.f;
}

// ---------------------------------------------------------------------------
// Fused main kernel: one block per (b, 4-row p-tile); 2048 blocks total so
// 8 blocks/CU are resident (grid-, not LDS-, limited before: R4 had only 4
// blocks/CU possible).  LDS ~18.5 KB -> 8 blocks/CU = 32 waves/CU.
// Phase A: D[pp][q] = sum_c z1[c,p]*z2[c,q]; coalesced float4 stream of
//          z2[b] (L2-resident); 1/|z2_q| folded into D at LDS-write time.
// Phase B: wave w owns p row w (threads aligned: t = pp*64 + lane); 4 n per
//          thread; img via L1; weight via full-wave xor-shuffle reduction;
//          LDS-atomic nacc[256] -> one global atomic per n per block.
// ---------------------------------------------------------------------------
__global__ __launch_bounds__(256, 8) void contrastive_fused(
    const float* __restrict__ z1,    // (B, C, HW)
    const float* __restrict__ z2,    // (B, C, HW)
    const float* __restrict__ img,   // (3, HW)
    const int*   __restrict__ nidx,  // (B, 2, HW, NEG)
    float* __restrict__ accSim,      // (B, NEG)
    float* __restrict__ accSim0)     // (B)
{
    __shared__ float As_s[CC * PT];  // [k][pp]  1 KB
    __shared__ float Dt_s[PT * HW];  // [pp][q] 16 KB (dot / |z2_q|)
    __shared__ float nacc[NEGN];     //          1 KB
    __shared__ float z1sqs[PT];

    const int t    = threadIdx.x;
    const int b    = blockIdx.x >> 8;
    const int tile = blockIdx.x & (NTILE - 1);
    const int p0   = tile * PT;

    const int lane = t & 63;     // n-group lane (full wave per p)
    const int pp_b = t >> 6;     // p handled by this thread in phase B
    const int p_b  = p0 + pp_b;

    // ---- prefetch nidx early (n = lane + 64*j; 256B coalesced per wave) ----
    int rr[4], cc_[4];
    const size_t nbase = ((size_t)(b * 2) * HW + p_b) * NEGN;
    #pragma unroll
    for (int j = 0; j < 4; ++j) {
        rr[j]  = nidx[nbase + lane + 64 * j];
        cc_[j] = nidx[nbase + (size_t)HW * NEGN + lane + 64 * j];
    }

    // ---- stage z1 panel (one element per thread); zero nacc ----
    {
        const int c = t >> 2, pp = t & 3;
        As_s[t] = z1[((size_t)(b * CC + c)) * HW + p0 + pp];
    }
    nacc[t] = 0.f;
    __syncthreads();

    if (t < PT) {
        float s = 0.f;
        #pragma unroll
        for (int c = 0; c < CC; ++c) { const float v = As_s[c * PT + t]; s += v * v; }
        z1sqs[t] = s;
    }

    // ---- phase A: GEMM, thread t owns q = 4t..4t+3 for the 4 p rows ----
    const float4* __restrict__ z2f4 =
        reinterpret_cast<const float4*>(z2 + (size_t)b * CC * HW);
    float4 acc[PT];
    #pragma unroll
    for (int pp = 0; pp < PT; ++pp) acc[pp] = make_float4(0.f, 0.f, 0.f, 0.f);
    float4 sq = make_float4(0.f, 0.f, 0.f, 0.f);

    #pragma unroll 8
    for (int k = 0; k < CC; ++k) {
        const float4 bv = z2f4[k * (HW / 4) + t];
        const float4 av = reinterpret_cast<const float4*>(As_s)[k];  // [pp 0..3]
        sq.x = fmaf(bv.x, bv.x, sq.x);
        sq.y = fmaf(bv.y, bv.y, sq.y);
        sq.z = fmaf(bv.z, bv.z, sq.z);
        sq.w = fmaf(bv.w, bv.w, sq.w);
        const float avv[4] = {av.x, av.y, av.z, av.w};
        #pragma unroll
        for (int pp = 0; pp < PT; ++pp) {
            acc[pp].x = fmaf(avv[pp], bv.x, acc[pp].x);
            acc[pp].y = fmaf(avv[pp], bv.y, acc[pp].y);
            acc[pp].z = fmaf(avv[pp], bv.z, acc[pp].z);
            acc[pp].w = fmaf(avv[pp], bv.w, acc[pp].w);
        }
    }
    // fold 1/|z2_q| into D at write time (|z2_q| ~ 8, far from eps)
    const float4 rp = make_float4(
        1.0f / fmaxf(sqrtf(sq.x), 1e-20f), 1.0f / fmaxf(sqrtf(sq.y), 1e-20f),
        1.0f / fmaxf(sqrtf(sq.z), 1e-20f), 1.0f / fmaxf(sqrtf(sq.w), 1e-20f));
    float4* Dt4 = reinterpret_cast<float4*>(Dt_s);
    #pragma unroll
    for (int pp = 0; pp < PT; ++pp) {
        float4 v = acc[pp];
        v.x *= rp.x; v.y *= rp.y; v.z *= rp.z; v.w *= rp.w;
        Dt4[pp * (HW / 4) + t] = v;
    }
    __syncthreads();

    // ---- phase B: gather + weight + sim; img via L1 (12 KB, hot) ----
    const float z1sq = z1sqs[pp_b];
    const float rz1  = 1.0f / fmaxf(sqrtf(z1sq), 1e-20f);
    const float cen0 = img[p_b], cen1 = img[HW + p_b], cen2 = img[2 * HW + p_b];
    const float hp = (float)(p_b >> 5), wp = (float)(p_b & 31);

    float se = 0.f, sr = 0.f;
    float cosv[4];
    #pragma unroll
    for (int j = 0; j < 4; ++j) {
        const int q = rr[j] * WW + cc_[j];
        const float dh = hp - (float)rr[j], dw = wp - (float)cc_[j];
        se += dh * dh + dw * dw;
        const float d0 = cen0 - img[q];
        const float d1 = cen1 - img[HW + q];
        const float d2 = cen2 - img[2 * HW + q];
        sr += d0 * d0 + d1 * d1 + d2 * d2;
        cosv[j] = Dt_s[pp_b * HW + q] * rz1;
    }
    // full-wave reduction: all 64 lanes of this wave share one p
    #pragma unroll
    for (int off = 32; off; off >>= 1) {
        se += __shfl_xor(se, off);
        sr += __shfl_xor(sr, off);
    }
    const float euc_norm = sqrtf((float)((HH - 1) * (HH - 1) + (WW - 1) * (WW - 1)));
    const float weight = sqrtf(se) / euc_norm * FACTOR +
                         sqrtf(sr) / sqrtf(3.0f) * (1.0f - FACTOR);

    // accumulate over pp via LDS atomics (4-way same-address -> cheap)
    #pragma unroll
    for (int j = 0; j < 4; ++j)
        atomicAdd(&nacc[lane + 64 * j], fminf(fabsf(cosv[j] * weight), 1.0f));
    __syncthreads();

    atomicAdd(accSim + b * NEGN + t, nacc[t]);

    if (t < PT) {
        const float c0 = z1sq / fmaxf(z1sq, EPSF);
        float s0 = fminf(fabsf(c0), 1.0f);
        s0 += __shfl_xor(s0, 1);
        s0 += __shfl_xor(s0, 2);
        if (t == 0) atomicAdd(accSim0 + b, s0);
    }
}

// ---------------------------------------------------------------------------
// Finalize: 8 KB in, 3 floats out; one block.
// ---------------------------------------------------------------------------
__global__ __launch_bounds__(256) void finalize(
    const float* __restrict__ accSim,
    const float* __restrict__ accSim0,
    float* __restrict__ out)
{
    const int t = threadIdx.x;
    float ssum = 0.f, lsum = 0.f;
    #pragma unroll
    for (int b = 0; b < BB; ++b) {
        const float s = accSim[b * NEGN + t] * (1.0f / HW) * (1.0f / TEMP);
        ssum += s;
        lsum += fmaxf(log1pf(-s), -100.0f);
    }
    __shared__ float rs[4], rl[4];
    #pragma unroll
    for (int off = 32; off; off >>= 1) {
        ssum += __shfl_down(ssum, off);
        lsum += __shfl_down(lsum, off);
    }
    if ((t & 63) == 0) { rs[t >> 6] = ssum; rl[t >> 6] = lsum; }
    __syncthreads();

    if (t == 0) {
        const float S = rs[0] + rs[1] + rs[2] + rs[3];
        const float L = rl[0] + rl[1] + rl[2] + rl[3];
        float logpsum = 0.f, sim0sum = 0.f;
        #pragma unroll
        for (int b = 0; b < BB; ++b) {
            const float s0 = accSim0[b] * (1.0f / HW);
            sim0sum += s0;
            logpsum += fmaxf(logf(s0), -100.0f);
        }
        out[0] = -(logpsum + L) / ((float)(NEGN + 1) * (float)BB);
        out[1] = sim0sum / (float)BB;
        out[2] = S / (float)NEGN * TEMP / (float)BB;
    }
}

extern "C" void kernel_launch(void* const* d_in, const int* in_sizes, int n_in,
                              void* d_out, int out_size, void* d_ws, size_t ws_size,
                              hipStream_t stream) {
    const float* v1   = (const float*)d_in[0];
    const float* v2   = (const float*)d_in[1];
    const float* img  = (const float*)d_in[2];
    const int*   nidx = (const int*)  d_in[3];

    float* accSim  = (float*)d_ws;            // B*NEG
    float* accSim0 = accSim + BB * NEGN;      // B

    init_acc<<<(BB * NEGN + BB + 255) / 256, 256, 0, stream>>>(accSim);
    contrastive_fused<<<BB * NTILE, 256, 0, stream>>>(
        v1, v2, img, nidx, accSim, accSim0);
    finalize<<<1, 256, 0, stream>>>(accSim, accSim0, (float*)d_out);
}

// Round 6
// 114.954 us; speedup vs baseline: 1.1185x; 1.1185x over previous
//
#include <hip/hip_runtime.h>
#include <math.h>

#define BB 8
#define CC 64
#define HH 32
#define WW 32
#define HW 1024
#define NEGN 256
#define TEMP 2.0f
#define FACTOR 0.8f
#define EPSF 1e-8f

// ws float offsets
#define WS_ACC   0                      // accSim [BB*NEGN]
#define WS_ACC0  (BB * NEGN)            // accSim0 [BB]
#define WS_DN    32768                  // Dn [BB*HW*HW] fp32 (32 MB), 128KB-aligned

// ---------------------------------------------------------------------------
__global__ __launch_bounds__(256) void init_acc(float* __restrict__ acc) {
    const int i = blockIdx.x * 256 + threadIdx.x;
    if (i < BB * NEGN + BB) acc[i] = 0.f;
}

// ---------------------------------------------------------------------------
// Tiled GEMM: Dn[b, p, q] = (z1_p . z2_q) / (|z1_p| |z2_q|).
// Grid (16,16,8): 64x64 output tile, K=64 staged whole (As/Bs 16 KB each).
// Tile norms computed from the staged LDS tiles (threads 0..127) and folded
// into the write; sim0 (per-p, q-independent) accumulated by qtile-0 blocks.
// z2 staging traffic: 2048 blocks x 32 KB = 64 MB (vs 536 MB in R5's fused).
// ---------------------------------------------------------------------------
__global__ __launch_bounds__(256) void gemm_dn(
    const float* __restrict__ z1,    // (B, C, HW)
    const float* __restrict__ z2,    // (B, C, HW)
    float* __restrict__ Dn,          // (B, HW, HW)
    float* __restrict__ accSim0)     // (B)
{
    __shared__ float As[CC * 64];    // [c][pp] 16 KB
    __shared__ float Bs[CC * 64];    // [c][qq] 16 KB
    __shared__ float rzs[128];       // [0:64) 1/|z1_p|, [64:128) 1/|z2_q|

    const int t  = threadIdx.x;
    const int q0 = blockIdx.x * 64;
    const int p0 = blockIdx.y * 64;
    const int b  = blockIdx.z;
    const float* z1b = z1 + (size_t)b * CC * HW;
    const float* z2b = z2 + (size_t)b * CC * HW;

    #pragma unroll
    for (int r = 0; r < 4; ++r) {
        const int e = r * 1024 + t * 4;      // element in [0, 4096)
        const int c = e >> 6, x = e & 63;
        reinterpret_cast<float4*>(As)[e >> 2] =
            *reinterpret_cast<const float4*>(z1b + c * HW + p0 + x);
        reinterpret_cast<float4*>(Bs)[e >> 2] =
            *reinterpret_cast<const float4*>(z2b + c * HW + q0 + x);
    }
    __syncthreads();

    // tile norms from LDS (stride-1 across lanes -> conflict-free)
    if (t < 128) {
        const int i = t & 63;
        const float* src = (t < 64) ? As : Bs;
        float s = 0.f;
        #pragma unroll
        for (int c = 0; c < CC; ++c) { const float v = src[c * 64 + i]; s += v * v; }
        rzs[t] = 1.0f / fmaxf(sqrtf(s), 1e-20f);
        // sim0 contribution (q-independent): only qtile-0 blocks emit it
        if (t < 64 && blockIdx.x == 0) {
            float s0 = fminf(fabsf(s / fmaxf(s, EPSF)), 1.0f);
            #pragma unroll
            for (int off = 32; off; off >>= 1) s0 += __shfl_xor(s0, off);
            if (i == 0) atomicAdd(accSim0 + b, s0);
        }
    }

    // thread (tp, tq) computes the 4x4 block at (p0+4tp, q0+4tq)
    const int tp = t >> 4, tq = t & 15;
    float4 a0 = make_float4(0.f, 0.f, 0.f, 0.f), a1 = a0, a2 = a0, a3 = a0;
    #pragma unroll 8
    for (int k = 0; k < CC; ++k) {
        const float4 b4 = *reinterpret_cast<const float4*>(Bs + k * 64 + tq * 4);
        const float4 a4 = *reinterpret_cast<const float4*>(As + k * 64 + tp * 4);
        a0.x = fmaf(a4.x, b4.x, a0.x); a0.y = fmaf(a4.x, b4.y, a0.y);
        a0.z = fmaf(a4.x, b4.z, a0.z); a0.w = fmaf(a4.x, b4.w, a0.w);
        a1.x = fmaf(a4.y, b4.x, a1.x); a1.y = fmaf(a4.y, b4.y, a1.y);
        a1.z = fmaf(a4.y, b4.z, a1.z); a1.w = fmaf(a4.y, b4.w, a1.w);
        a2.x = fmaf(a4.z, b4.x, a2.x); a2.y = fmaf(a4.z, b4.y, a2.y);
        a2.z = fmaf(a4.z, b4.z, a2.z); a2.w = fmaf(a4.z, b4.w, a2.w);
        a3.x = fmaf(a4.w, b4.x, a3.x); a3.y = fmaf(a4.w, b4.y, a3.y);
        a3.z = fmaf(a4.w, b4.z, a3.z); a3.w = fmaf(a4.w, b4.w, a3.w);
    }
    __syncthreads();   // rzs writes (t<128) happen-before this; safe to read

    const float4 r2 = *reinterpret_cast<const float4*>(rzs + 64 + tq * 4);
    const float r10 = rzs[tp * 4 + 0], r11 = rzs[tp * 4 + 1];
    const float r12 = rzs[tp * 4 + 2], r13 = rzs[tp * 4 + 3];
    float4* drow;
    #define WRITE_ROW(i, accv, r1v)                                           \
        drow = reinterpret_cast<float4*>(                                     \
            Dn + ((size_t)(b * HW + p0 + tp * 4 + i)) * HW + q0 + tq * 4);    \
        *drow = make_float4(accv.x * r1v * r2.x, accv.y * r1v * r2.y,         \
                            accv.z * r1v * r2.z, accv.w * r1v * r2.w);
    WRITE_ROW(0, a0, r10)
    WRITE_ROW(1, a1, r11)
    WRITE_ROW(2, a2, r12)
    WRITE_ROW(3, a3, r13)
    #undef WRITE_ROW
}

// ---------------------------------------------------------------------------
// Gather: one block per (b, 4 p-rows); wave w owns p-row w; 4 n per thread.
// Reads: nidx coalesced; img via L1 (12 KB hot); Dn 4B gathers within one
// 4 KB row (L1-cached across the 4 accesses). LDS-atomic nacc -> one global
// atomic per n per block.
// ---------------------------------------------------------------------------
__global__ __launch_bounds__(256) void gather_sim(
    const float* __restrict__ Dn,    // (B, HW, HW) normalized cos
    const float* __restrict__ img,   // (3, HW)
    const int*   __restrict__ nidx,  // (B, 2, HW, NEG)
    float* __restrict__ accSim)      // (B, NEG)
{
    __shared__ float nacc[NEGN];
    const int t    = threadIdx.x;
    const int b    = blockIdx.x >> 8;
    const int tile = blockIdx.x & 255;
    const int lane = t & 63;
    const int p    = tile * 4 + (t >> 6);

    nacc[t] = 0.f;

    int rr[4], cc_[4];
    const size_t nbase = ((size_t)(b * 2) * HW + p) * NEGN;
    #pragma unroll
    for (int j = 0; j < 4; ++j) {
        rr[j]  = nidx[nbase + lane + 64 * j];
        cc_[j] = nidx[nbase + (size_t)HW * NEGN + lane + 64 * j];
    }
    __syncthreads();

    const float cen0 = img[p], cen1 = img[HW + p], cen2 = img[2 * HW + p];
    const float hp = (float)(p >> 5), wp = (float)(p & 31);
    const float* __restrict__ Drow = Dn + ((size_t)(b * HW + p)) * HW;

    float se = 0.f, sr = 0.f;
    float cosv[4];
    #pragma unroll
    for (int j = 0; j < 4; ++j) {
        const int q = rr[j] * WW + cc_[j];
        const float dh = hp - (float)rr[j], dw = wp - (float)cc_[j];
        se += dh * dh + dw * dw;
        const float d0 = cen0 - img[q];
        const float d1 = cen1 - img[HW + q];
        const float d2 = cen2 - img[2 * HW + q];
        sr += d0 * d0 + d1 * d1 + d2 * d2;
        cosv[j] = Drow[q];
    }
    #pragma unroll
    for (int off = 32; off; off >>= 1) {
        se += __shfl_xor(se, off);
        sr += __shfl_xor(sr, off);
    }
    const float euc_norm = sqrtf((float)((HH - 1) * (HH - 1) + (WW - 1) * (WW - 1)));
    const float weight = sqrtf(se) / euc_norm * FACTOR +
                         sqrtf(sr) / sqrtf(3.0f) * (1.0f - FACTOR);

    #pragma unroll
    for (int j = 0; j < 4; ++j)
        atomicAdd(&nacc[lane + 64 * j], fminf(fabsf(cosv[j] * weight), 1.0f));
    __syncthreads();

    atomicAdd(accSim + b * NEGN + t, nacc[t]);
}

// ---------------------------------------------------------------------------
__global__ __launch_bounds__(256) void finalize(
    const float* __restrict__ accSim,
    const float* __restrict__ accSim0,
    float* __restrict__ out)
{
    const int t = threadIdx.x;
    float ssum = 0.f, lsum = 0.f;
    #pragma unroll
    for (int b = 0; b < BB; ++b) {
        const float s = accSim[b * NEGN + t] * (1.0f / HW) * (1.0f / TEMP);
        ssum += s;
        lsum += fmaxf(log1pf(-s), -100.0f);
    }
    __shared__ float rs[4], rl[4];
    #pragma unroll
    for (int off = 32; off; off >>= 1) {
        ssum += __shfl_down(ssum, off);
        lsum += __shfl_down(lsum, off);
    }
    if ((t & 63) == 0) { rs[t >> 6] = ssum; rl[t >> 6] = lsum; }
    __syncthreads();

    if (t == 0) {
        const float S = rs[0] + rs[1] + rs[2] + rs[3];
        const float L = rl[0] + rl[1] + rl[2] + rl[3];
        float logpsum = 0.f, sim0sum = 0.f;
        #pragma unroll
        for (int b = 0; b < BB; ++b) {
            const float s0 = accSim0[b] * (1.0f / HW);
            sim0sum += s0;
            logpsum += fmaxf(logf(s0), -100.0f);
        }
        out[0] = -(logpsum + L) / ((float)(NEGN + 1) * (float)BB);
        out[1] = sim0sum / (float)BB;
        out[2] = S / (float)NEGN * TEMP / (float)BB;
    }
}

extern "C" void kernel_launch(void* const* d_in, const int* in_sizes, int n_in,
                              void* d_out, int out_size, void* d_ws, size_t ws_size,
                              hipStream_t stream) {
    const float* v1   = (const float*)d_in[0];
    const float* v2   = (const float*)d_in[1];
    const float* img  = (const float*)d_in[2];
    const int*   nidx = (const int*)  d_in[3];

    float* ws      = (float*)d_ws;
    float* accSim  = ws + WS_ACC;
    float* accSim0 = ws + WS_ACC0;
    float* Dn      = ws + WS_DN;

    init_acc<<<(BB * NEGN + BB + 255) / 256, 256, 0, stream>>>(accSim);
    gemm_dn<<<dim3(HW / 64, HW / 64, BB), 256, 0, stream>>>(v1, v2, Dn, accSim0);
    gather_sim<<<BB * (HW / 4), 256, 0, stream>>>(Dn, img, nidx, accSim);
    finalize<<<1, 256, 0, stream>>>(accSim, accSim0, (float*)d_out);
}

// Round 7
// 111.552 us; speedup vs baseline: 1.1526x; 1.0305x over previous
//
#include <hip/hip_runtime.h>
#include <math.h>

#define BB 8
#define CC 64
#define HH 32
#define WW 32
#define HW 1024
#define NEGN 256
#define TEMP 2.0f
#define FACTOR 0.8f
#define EPSF 1e-8f

typedef __attribute__((ext_vector_type(8))) short short8;   // 8 bf16
typedef __attribute__((ext_vector_type(4))) float float4v;  // MFMA C/D

// ws byte offsets
#define WSB_ACC  0            // accSim  [BB*NEGN] f32 (8 KB)
#define WSB_S0   (1u << 20)   // s0part  [BB*16] f32
#define WSB_RZ1  (2u << 20)   // rz1 [BB*HW] f32
#define WSB_RZ2  (3u << 20)   // rz2 [BB*HW] f32
#define WSB_Z1T  (4u << 20)   // z1t [BB*HW*CC] bf16 (1 MB)
#define WSB_Z2T  (8u << 20)   // z2t (1 MB)
#define WSB_DN   (16u << 20)  // Dn  [BB*HW*HW] f16 (16.8 MB)

__device__ __forceinline__ unsigned short f2bf(float x) {
    unsigned u = __float_as_uint(x);
    return (unsigned short)((u + 0x7FFFu + ((u >> 16) & 1u)) >> 16);
}

// ---------------------------------------------------------------------------
// prep: transpose+convert z{1,2} (B,C,HW) f32 -> z{1,2}t (B,HW,C) bf16;
// fp32 row norms -> rz{1,2}; sim0 partials (no atomics); zero accSim.
// 256 blocks: tensor(1b) x b(3b) x ptile(4b); each handles 64 p x all 64 c.
// ---------------------------------------------------------------------------
__global__ __launch_bounds__(256) void prep(
    const float* __restrict__ z1, const float* __restrict__ z2,
    unsigned short* __restrict__ z1t, unsigned short* __restrict__ z2t,
    float* __restrict__ rz1, float* __restrict__ rz2,
    float* __restrict__ accSim, float* __restrict__ s0part)
{
    __shared__ float tile[CC * 64];   // [c][pp] 16 KB
    const int t = threadIdx.x;
    const int bid = blockIdx.x;
    const int tensor = bid >> 7;
    const int b  = (bid >> 4) & 7;
    const int pt = bid & 15;
    const int p0 = pt * 64;

    if (bid < 8) accSim[bid * 256 + t] = 0.f;   // zero 2048-float accumulator

    const float* __restrict__ src = (tensor ? z2 : z1) + (size_t)b * CC * HW;
    #pragma unroll
    for (int r = 0; r < 16; ++r) {
        const int idx = r * 256 + t;                       // [c(6b)][pp(6b)]
        tile[idx] = src[(idx >> 6) * HW + p0 + (idx & 63)];
    }
    __syncthreads();

    if (t < 64) {   // wave 0: fp32 norms + sim0
        float s = 0.f;
        #pragma unroll
        for (int c = 0; c < CC; ++c) { const float v = tile[c * 64 + t]; s += v * v; }
        const float rz = 1.0f / fmaxf(sqrtf(s), 1e-20f);
        (tensor ? rz2 : rz1)[b * HW + p0 + t] = rz;
        if (tensor == 0) {
            float s0 = fminf(fabsf(s / fmaxf(s, EPSF)), 1.0f);
            #pragma unroll
            for (int off = 32; off; off >>= 1) s0 += __shfl_xor(s0, off);
            if (t == 0) s0part[b * 16 + pt] = s0;
        }
    }

    // transposed bf16 write: thread t owns row pp=t>>2, c-range (t&3)*16..+16
    unsigned short* __restrict__ dst =
        (tensor ? z2t : z1t) + ((size_t)(b * HW) + p0) * CC;
    const int pp = t >> 2, c0 = (t & 3) * 16;
    unsigned u[8];
    #pragma unroll
    for (int j = 0; j < 8; ++j) {
        const unsigned short lo = f2bf(tile[(c0 + 2 * j)     * 64 + pp]);
        const unsigned short hi = f2bf(tile[(c0 + 2 * j + 1) * 64 + pp]);
        u[j] = (unsigned)lo | ((unsigned)hi << 16);
    }
    uint4* o = (uint4*)(dst + pp * CC + c0);
    o[0] = make_uint4(u[0], u[1], u[2], u[3]);
    o[1] = make_uint4(u[4], u[5], u[6], u[7]);
}

// ---------------------------------------------------------------------------
// gemm_dn: Dn[b,p,q] = cos(z1_p, z2_q) as fp16, via mfma_f32_16x16x32_bf16.
// Grid (16,16,8), 256 thr = 4 waves; wave w owns p-subtile row w of a 64x64
// tile. Fragments loaded straight from global (z*t rows are 16B/lane
// contiguous; A[m=lane&15][k=(lane>>4)*8+j], B symmetric). No LDS.
// ---------------------------------------------------------------------------
__global__ __launch_bounds__(256) void gemm_dn(
    const unsigned short* __restrict__ z1t,  // (B, HW, CC) bf16
    const unsigned short* __restrict__ z2t,  // (B, HW, CC) bf16
    const float* __restrict__ rz1, const float* __restrict__ rz2,
    _Float16* __restrict__ Dn)               // (B, HW, HW)
{
    const int t = threadIdx.x;
    const int lane = t & 63, w = t >> 6;
    const int q0 = blockIdx.x * 64, p0 = blockIdx.y * 64, b = blockIdx.z;
    const int l15 = lane & 15, l4 = lane >> 4;

    const short8* a_ptr = (const short8*)(
        z1t + ((size_t)(b * HW) + p0 + w * 16 + l15) * CC + l4 * 8);
    const short8 a0 = a_ptr[0];   // k in [0,32)
    const short8 a1 = a_ptr[4];   // k in [32,64)

    float4v acc[4];
    #pragma unroll
    for (int sn = 0; sn < 4; ++sn) acc[sn] = (float4v){0.f, 0.f, 0.f, 0.f};

    #pragma unroll
    for (int sn = 0; sn < 4; ++sn) {
        const short8* b_ptr = (const short8*)(
            z2t + ((size_t)(b * HW) + q0 + sn * 16 + l15) * CC + l4 * 8);
        acc[sn] = __builtin_amdgcn_mfma_f32_16x16x32_bf16(a0, b_ptr[0], acc[sn], 0, 0, 0);
        acc[sn] = __builtin_amdgcn_mfma_f32_16x16x32_bf16(a1, b_ptr[4], acc[sn], 0, 0, 0);
    }

    // epilogue: C/D row = (lane>>4)*4 + r, col = lane&15 (m89-verified)
    const int prow = p0 + w * 16 + l4 * 4;
    float r1[4];
    #pragma unroll
    for (int r = 0; r < 4; ++r) r1[r] = rz1[b * HW + prow + r];
    #pragma unroll
    for (int sn = 0; sn < 4; ++sn) {
        const int q = q0 + sn * 16 + l15;
        const float r2v = rz2[b * HW + q];
        #pragma unroll
        for (int r = 0; r < 4; ++r)
            Dn[((size_t)(b * HW) + prow + r) * HW + q] =
                (_Float16)(acc[sn][r] * r1[r] * r2v);
    }
}

// ---------------------------------------------------------------------------
// gather_sim: block = (b, 4 p-rows); stages the 4 contiguous Dn rows (8 KB)
// and img (12 KB) into LDS so all scattered reads are LDS ops. Wave w owns
// p-row w; 4 n per thread; weight via wave xor-reduce; LDS nacc -> one
// global atomic per n per block.
// ---------------------------------------------------------------------------
__global__ __launch_bounds__(256) void gather_sim(
    const _Float16* __restrict__ Dn,   // (B, HW, HW)
    const float* __restrict__ img,     // (3, HW)
    const int*   __restrict__ nidx,    // (B, 2, HW, NEG)
    float* __restrict__ accSim)        // (B, NEG)
{
    __shared__ _Float16 Dl[4 * HW];    //  8 KB
    __shared__ float imgl[3 * HW];     // 12 KB
    __shared__ float nacc[NEGN];       //  1 KB

    const int t    = threadIdx.x;
    const int b    = blockIdx.x >> 8;
    const int tile = blockIdx.x & 255;
    const int lane = t & 63;
    const int pp   = t >> 6;
    const int p    = tile * 4 + pp;

    nacc[t] = 0.f;

    // coalesced staging: Dn rows are contiguous (p, p+1, p+2, p+3)
    const float4* s4 = (const float4*)(Dn + ((size_t)(b * HW) + tile * 4) * HW);
    float4* d4 = (float4*)Dl;
    d4[t] = s4[t]; d4[t + 256] = s4[t + 256];
    const float4* i4 = (const float4*)img;
    float4* il4 = (float4*)imgl;
    il4[t] = i4[t]; il4[t + 256] = i4[t + 256]; il4[t + 512] = i4[t + 512];

    int rr[4], cc_[4];
    const size_t nbase = ((size_t)(b * 2) * HW + p) * NEGN;
    #pragma unroll
    for (int j = 0; j < 4; ++j) {
        rr[j]  = nidx[nbase + lane + 64 * j];
        cc_[j] = nidx[nbase + (size_t)HW * NEGN + lane + 64 * j];
    }
    __syncthreads();

    const float cen0 = imgl[p], cen1 = imgl[HW + p], cen2 = imgl[2 * HW + p];
    const float hp = (float)(p >> 5), wp = (float)(p & 31);

    float se = 0.f, sr = 0.f;
    float cosv[4];
    #pragma unroll
    for (int j = 0; j < 4; ++j) {
        const int q = rr[j] * WW + cc_[j];
        const float dh = hp - (float)rr[j], dw = wp - (float)cc_[j];
        se += dh * dh + dw * dw;
        const float d0 = cen0 - imgl[q];
        const float d1 = cen1 - imgl[HW + q];
        const float d2 = cen2 - imgl[2 * HW + q];
        sr += d0 * d0 + d1 * d1 + d2 * d2;
        cosv[j] = (float)Dl[pp * HW + q];
    }
    #pragma unroll
    for (int off = 32; off; off >>= 1) {
        se += __shfl_xor(se, off);
        sr += __shfl_xor(sr, off);
    }
    const float euc_norm = sqrtf((float)((HH - 1) * (HH - 1) + (WW - 1) * (WW - 1)));
    const float weight = sqrtf(se) / euc_norm * FACTOR +
                         sqrtf(sr) / sqrtf(3.0f) * (1.0f - FACTOR);

    #pragma unroll
    for (int j = 0; j < 4; ++j)
        atomicAdd(&nacc[lane + 64 * j], fminf(fabsf(cosv[j] * weight), 1.0f));
    __syncthreads();

    atomicAdd(accSim + b * NEGN + t, nacc[t]);
}

// ---------------------------------------------------------------------------
__global__ __launch_bounds__(256) void finalize(
    const float* __restrict__ accSim,
    const float* __restrict__ s0part,
    float* __restrict__ out)
{
    const int t = threadIdx.x;
    float ssum = 0.f, lsum = 0.f;
    #pragma unroll
    for (int b = 0; b < BB; ++b) {
        const float s = accSim[b * NEGN + t] * (1.0f / HW) * (1.0f / TEMP);
        ssum += s;
        lsum += fmaxf(log1pf(-s), -100.0f);
    }
    __shared__ float rs[4], rl[4], r0[2];   // r0: sim0sum, logpsum
    #pragma unroll
    for (int off = 32; off; off >>= 1) {
        ssum += __shfl_down(ssum, off);
        lsum += __shfl_down(lsum, off);
    }
    if ((t & 63) == 0) { rs[t >> 6] = ssum; rl[t >> 6] = lsum; }

    if (t == 0) {
        float s0m = 0.f, logp = 0.f;
        #pragma unroll
        for (int b = 0; b < BB; ++b) {
            float sb = 0.f;
            #pragma unroll
            for (int j = 0; j < 16; ++j) sb += s0part[b * 16 + j];
            const float s0 = sb * (1.0f / HW);
            s0m  += s0;
            logp += fmaxf(logf(s0), -100.0f);
        }
        r0[0] = s0m; r0[1] = logp;
    }
    __syncthreads();

    if (t == 0) {
        const float S = rs[0] + rs[1] + rs[2] + rs[3];
        const float L = rl[0] + rl[1] + rl[2] + rl[3];
        out[0] = -(r0[1] + L) / ((float)(NEGN + 1) * (float)BB);
        out[1] = r0[0] / (float)BB;
        out[2] = S / (float)NEGN * TEMP / (float)BB;
    }
}

extern "C" void kernel_launch(void* const* d_in, const int* in_sizes, int n_in,
                              void* d_out, int out_size, void* d_ws, size_t ws_size,
                              hipStream_t stream) {
    const float* v1   = (const float*)d_in[0];
    const float* v2   = (const float*)d_in[1];
    const float* img  = (const float*)d_in[2];
    const int*   nidx = (const int*)  d_in[3];

    char* base = (char*)d_ws;
    float*          accSim = (float*)(base + WSB_ACC);
    float*          s0part = (float*)(base + WSB_S0);
    float*          rz1    = (float*)(base + WSB_RZ1);
    float*          rz2    = (float*)(base + WSB_RZ2);
    unsigned short* z1t    = (unsigned short*)(base + WSB_Z1T);
    unsigned short* z2t    = (unsigned short*)(base + WSB_Z2T);
    _Float16*       Dn     = (_Float16*)(base + WSB_DN);

    prep<<<256, 256, 0, stream>>>(v1, v2, z1t, z2t, rz1, rz2, accSim, s0part);
    gemm_dn<<<dim3(16, 16, BB), 256, 0, stream>>>(z1t, z2t, rz1, rz2, Dn);
    gather_sim<<<BB * 256, 256, 0, stream>>>(Dn, img, nidx, accSim);
    finalize<<<1, 256, 0, stream>>>(accSim, s0part, (float*)d_out);
}